// Round 8
// baseline (376.616 us; speedup 1.0000x reference)
//
#include <hip/hip_runtime.h>
#include <hip/hip_bf16.h>

// THLSTM cell fused, MI355X gfx950 — round 8.
// BT=32 rows/WG, 4 waves, 40KB LDS -> 3-4 independent WGs/CU (12-16 waves/CU).
// Wave = 32 rows x 64 cols: 2 col-tile accs sharing one A stream.
// K=640 contiguous (hx k8 0..47, s k8 48..79 adjacent in LDS and weights).
// launch_bounds(256,2): the empirically-safe no-spill setting (VGPR~128).

constexpr int Btot = 65536;
constexpr int H    = 256;
constexpr int I    = 128;
constexpr int K1   = 384;    // [h|x]
constexpr int BT   = 32;     // batch rows per WG
constexpr int NTHR = 256;    // 4 waves
constexpr int SOFF = 24576;  // s-tile base: 48 k8 x 32 rows x 16B

typedef __bf16 bf16x8  __attribute__((ext_vector_type(8)));
typedef float  f32x16  __attribute__((ext_vector_type(16)));
typedef unsigned short ushort8 __attribute__((ext_vector_type(8)));

__device__ __forceinline__ unsigned short f2bf(float f) {
    unsigned u = __builtin_bit_cast(unsigned, f);
    u += 0x7fffu + ((u >> 16) & 1u);   // RNE
    return (unsigned short)(u >> 16);
}
__device__ __forceinline__ float bf2f(unsigned short s) {
    return __builtin_bit_cast(float, ((unsigned)s) << 16);
}
__device__ __forceinline__ float sigm(float x) {
    return __builtin_amdgcn_rcpf(1.0f + exp2f(-1.4426950408889634f * x));
}
__device__ __forceinline__ float tanh_f(float x) {
    return 1.0f - 2.0f * __builtin_amdgcn_rcpf(1.0f + exp2f(2.8853900817779268f * x));
}

// Weights to bf16, layout [k8][col][8]: elem (col, k=k8*8+e) at (k8*256+col)*8+e.
// w0: 48 k8 (K=384); per gate wg: 80 k8 (K=640: h|x|s), gates f,i,T,u,o.
__global__ void convert_w(const float* __restrict__ Wh, const float* __restrict__ Wx,
                          const float* __restrict__ Ws, unsigned short* __restrict__ w0,
                          unsigned short* __restrict__ wg) {
    const int t  = blockIdx.x * blockDim.x + threadIdx.x;
    const int N0 = 48 * 2048;        // 98304
    const int N1 = 5 * 80 * 2048;    // 819200
    if (t < N0) {
        const int k8 = t >> 11, rem = t & 2047;
        const int col = rem >> 3, e = rem & 7;
        const int k = k8 * 8 + e;
        const float v = (k < H) ? Wh[col * H + k] : Wx[col * I + (k - H)];
        w0[t] = f2bf(v);
    } else if (t < N0 + N1) {
        const int u   = t - N0;
        const int g1  = u / 163840;
        const int rem = u - g1 * 163840;
        const int k8  = rem >> 11;
        const int r2  = rem & 2047;
        const int col = r2 >> 3, e = r2 & 7;
        const int k   = k8 * 8 + e;
        const int g   = g1 + 1;
        float v;
        if (k < H)        v = Wh[g * H * H + col * H + k];
        else if (k < K1)  v = Wx[g * H * I + col * I + (k - H)];
        else              v = Ws[g1 * H * H + col * H + (k - K1)];
        wg[u] = f2bf(v);
    }
}

// K-loop: 1 A stream (32 rows), 2 B streams (2 col tiles). B-ring 4, A-ring 2.
template<int NIT>
__device__ __forceinline__ void gemm_pipe(const unsigned char* Ab, int abase,
        const unsigned short* __restrict__ Wp, f32x16& acc0, f32x16& acc1) {
    bf16x8 b0[4], b1[4], a[2];
    #pragma unroll
    for (int i = 0; i < 4; ++i) {
        b0[i] = *(const bf16x8*)(Wp + i * 4096);
        b1[i] = *(const bf16x8*)(Wp + i * 4096 + 256);
    }
    #pragma unroll
    for (int i = 0; i < 2; ++i)
        a[i] = *(const bf16x8*)(Ab + abase + i * 1024);
    #pragma unroll
    for (int i = 0; i < NIT; ++i) {
        const bf16x8 av = a[i & 1], bv0 = b0[i & 3], bv1 = b1[i & 3];
        if (i + 2 < NIT)
            a[i & 1] = *(const bf16x8*)(Ab + abase + (i + 2) * 1024);
        if (i + 4 < NIT) {
            b0[i & 3] = *(const bf16x8*)(Wp + (i + 4) * 4096);
            b1[i & 3] = *(const bf16x8*)(Wp + (i + 4) * 4096 + 256);
        }
        acc0 = __builtin_amdgcn_mfma_f32_32x32x16_bf16(av, bv0, acc0, 0, 0, 0);
        acc1 = __builtin_amdgcn_mfma_f32_32x32x16_bf16(av, bv1, acc1, 0, 0, 0);
    }
}

__global__ __launch_bounds__(NTHR, 2) void thlstm_fused(
        const float* __restrict__ x_t, const float* __restrict__ delta_t,
        const float* __restrict__ h_prev, const float* __restrict__ c_prev,
        const float* __restrict__ Wst, const float* __restrict__ bias,
        const unsigned short* __restrict__ w0, const unsigned short* __restrict__ wg,
        float* __restrict__ out) {
    __shared__ __align__(16) unsigned char Abuf[40960];   // 24KB hx + 16KB s
    const int tid = threadIdx.x;
    const int b0  = blockIdx.x * BT;

    // ---- stage h|x bf16, fragment order: chunk (k8, row) at (k8*32+row)*16 ----
    #pragma unroll
    for (int it = 0; it < 6; ++it) {
        const int c   = it * NTHR + tid;
        const int k8  = c >> 5, row = c & 31;
        const float* src = (k8 < 32) ? (h_prev + (size_t)(b0 + row) * H + k8 * 8)
                                     : (x_t    + (size_t)(b0 + row) * I + (k8 - 32) * 8);
        const float4 v0 = ((const float4*)src)[0];
        const float4 v1 = ((const float4*)src)[1];
        ushort8 p;
        p[0] = f2bf(v0.x); p[1] = f2bf(v0.y); p[2] = f2bf(v0.z); p[3] = f2bf(v0.w);
        p[4] = f2bf(v1.x); p[5] = f2bf(v1.y); p[6] = f2bf(v1.z); p[7] = f2bf(v1.w);
        *(ushort8*)(Abuf + (k8 * 32 + row) * 16) = p;
    }
    __syncthreads();

    const int lane  = tid & 63;
    const int wv    = tid >> 6;           // 0..3 -> cols wv*64 .. wv*64+63
    const int half  = lane >> 5;
    const int l31   = lane & 31;
    const int rbase = 4 * half;
    const int abase = half * 512 + l31 * 16;
    const int wlo   = half * 2048 + (wv * 64 + l31) * 8;   // shorts; tile1 = +256

    // ---- gate s: K=384 ----
    {
        f32x16 acc0, acc1;
        #pragma unroll
        for (int r = 0; r < 16; ++r) { acc0[r] = 0.f; acc1[r] = 0.f; }
        gemm_pipe<24>(Abuf, abase, w0 + wlo, acc0, acc1);
        #pragma unroll
        for (int ct = 0; ct < 2; ++ct) {
            const int col = wv * 64 + ct * 32 + l31;
            const float wst = Wst[col];
            const float bs  = bias[col];
            #pragma unroll
            for (int r = 0; r < 16; ++r) {
                const int mrow = (r & 3) + 8 * (r >> 2) + rbase;
                const float av = ct ? acc1[r] : acc0[r];
                const float sv = tanh_f(av + delta_t[b0 + mrow] * wst + bs);
                *(unsigned short*)(Abuf + SOFF + ((col >> 3) * 32 + mrow) * 16 + (col & 7) * 2) = f2bf(sv);
            }
        }
    }
    __syncthreads();

    float    cacc[2][16];
    unsigned ipk[2][8];

    // ---- gate f (wg 0, bias 1): c = f * c_prev ----
    {
        f32x16 ac0, ac1;
        #pragma unroll
        for (int r = 0; r < 16; ++r) { ac0[r] = 0.f; ac1[r] = 0.f; }
        gemm_pipe<40>(Abuf, abase, wg + 0 * 163840 + wlo, ac0, ac1);
        #pragma unroll
        for (int ct = 0; ct < 2; ++ct) {
            const int col = wv * 64 + ct * 32 + l31;
            const float bg = bias[1 * H + col];
            #pragma unroll
            for (int r = 0; r < 16; ++r) {
                const int mrow = (r & 3) + 8 * (r >> 2) + rbase;
                const size_t idx = (size_t)(b0 + mrow) * H + col;
                cacc[ct][r] = sigm((ct ? ac1[r] : ac0[r]) + bg) * c_prev[idx];
            }
        }
    }
    // ---- gate T (wg 2, bias 3): c += T * s (s from LDS) ----
    {
        f32x16 ac0, ac1;
        #pragma unroll
        for (int r = 0; r < 16; ++r) { ac0[r] = 0.f; ac1[r] = 0.f; }
        gemm_pipe<40>(Abuf, abase, wg + 2 * 163840 + wlo, ac0, ac1);
        #pragma unroll
        for (int ct = 0; ct < 2; ++ct) {
            const int col = wv * 64 + ct * 32 + l31;
            const float bg = bias[3 * H + col];
            #pragma unroll
            for (int r = 0; r < 16; ++r) {
                const int mrow = (r & 3) + 8 * (r >> 2) + rbase;
                const float sv = bf2f(*(const unsigned short*)(Abuf + SOFF +
                        ((col >> 3) * 32 + mrow) * 16 + (col & 7) * 2));
                cacc[ct][r] += sigm((ct ? ac1[r] : ac0[r]) + bg) * sv;
            }
        }
    }
    // ---- gate i (wg 1, bias 2): keep packed ----
    {
        f32x16 ac0, ac1;
        #pragma unroll
        for (int r = 0; r < 16; ++r) { ac0[r] = 0.f; ac1[r] = 0.f; }
        gemm_pipe<40>(Abuf, abase, wg + 1 * 163840 + wlo, ac0, ac1);
        #pragma unroll
        for (int ct = 0; ct < 2; ++ct) {
            const int col = wv * 64 + ct * 32 + l31;
            const float bg = bias[2 * H + col];
            float tmpf = 0.f;
            #pragma unroll
            for (int r = 0; r < 16; ++r) {
                const float sg = sigm((ct ? ac1[r] : ac0[r]) + bg);
                if ((r & 1) == 0) tmpf = sg;
                else ipk[ct][r >> 1] = (unsigned)f2bf(tmpf) | ((unsigned)f2bf(sg) << 16);
            }
        }
    }
    // ---- gate u (wg 3, bias 4): c += i * tanh(u) ----
    {
        f32x16 ac0, ac1;
        #pragma unroll
        for (int r = 0; r < 16; ++r) { ac0[r] = 0.f; ac1[r] = 0.f; }
        gemm_pipe<40>(Abuf, abase, wg + 3 * 163840 + wlo, ac0, ac1);
        #pragma unroll
        for (int ct = 0; ct < 2; ++ct) {
            const int col = wv * 64 + ct * 32 + l31;
            const float bg = bias[4 * H + col];
            #pragma unroll
            for (int r = 0; r < 16; ++r) {
                const float iv = bf2f((unsigned short)((ipk[ct][r >> 1] >> ((r & 1) * 16)) & 0xffffu));
                cacc[ct][r] += iv * tanh_f((ct ? ac1[r] : ac0[r]) + bg);
            }
        }
    }
    // ---- gate o (wg 4, bias 5): outputs ----
    {
        f32x16 ac0, ac1;
        #pragma unroll
        for (int r = 0; r < 16; ++r) { ac0[r] = 0.f; ac1[r] = 0.f; }
        gemm_pipe<40>(Abuf, abase, wg + 4 * 163840 + wlo, ac0, ac1);
        #pragma unroll
        for (int ct = 0; ct < 2; ++ct) {
            const int col = wv * 64 + ct * 32 + l31;
            const float bg = bias[5 * H + col];
            #pragma unroll
            for (int r = 0; r < 16; ++r) {
                const int mrow = (r & 3) + 8 * (r >> 2) + rbase;
                const size_t idx = (size_t)(b0 + mrow) * H + col;
                const float c = cacc[ct][r];
                out[idx] = sigm((ct ? ac1[r] : ac0[r]) + bg) * tanh_f(c);
                out[(size_t)Btot * H + idx] = c;
            }
        }
    }
}

extern "C" void kernel_launch(void* const* d_in, const int* in_sizes, int n_in,
                              void* d_out, int out_size, void* d_ws, size_t ws_size,
                              hipStream_t stream) {
    (void)in_sizes; (void)n_in; (void)out_size; (void)ws_size;
    const float* x_t    = (const float*)d_in[0];
    const float* delta  = (const float*)d_in[1];
    const float* h_prev = (const float*)d_in[2];
    const float* c_prev = (const float*)d_in[3];
    const float* Wh     = (const float*)d_in[4];
    const float* Wx     = (const float*)d_in[5];
    const float* Ws     = (const float*)d_in[6];
    const float* Wst    = (const float*)d_in[7];
    const float* bias   = (const float*)d_in[8];
    float* out = (float*)d_out;

    unsigned short* w0 = (unsigned short*)d_ws;   // 48*2048 bf16
    unsigned short* wg = w0 + 48 * 2048;          // 5*80*2048 bf16

    const int total = 48 * 2048 + 5 * 80 * 2048;  // 917504
    convert_w<<<(total + 255) / 256, 256, 0, stream>>>(Wh, Wx, Ws, w0, wg);
    thlstm_fused<<<Btot / BT, NTHR, 0, stream>>>(x_t, delta, h_prev, c_prev,
                                                 Wst, bias, w0, wg, out);
}

// Round 9
// 209.463 us; speedup vs baseline: 1.7980x; 1.7980x over previous
//
#include <hip/hip_runtime.h>
#include <hip/hip_bf16.h>

// THLSTM cell fused, MI355X gfx950 — round 9.
// Lean-wave structure: BT=32 rows/WG, 8 waves, each wave ONE 32x32 output
// tile (single acc chain -> ~95 total regs incl. AGPR). launch_bounds(512,4)
// caps total at 128 regs = 4 waves/SIMD (16 waves/CU, 2 WGs resident).
// LDS 40KB: hx k8 0..47 + s k8 48..79 contiguous => one K=640 A-stream.

constexpr int Btot = 65536;
constexpr int H    = 256;
constexpr int I    = 128;
constexpr int K1   = 384;    // [h|x]
constexpr int BT   = 32;     // batch rows per WG
constexpr int NTHR = 512;    // 8 waves
constexpr int SOFF = 24576;  // s-tile base: 48 k8 x 32 rows x 16B

typedef __bf16 bf16x8  __attribute__((ext_vector_type(8)));
typedef float  f32x16  __attribute__((ext_vector_type(16)));
typedef unsigned short ushort8 __attribute__((ext_vector_type(8)));

__device__ __forceinline__ unsigned short f2bf(float f) {
    unsigned u = __builtin_bit_cast(unsigned, f);
    u += 0x7fffu + ((u >> 16) & 1u);   // RNE
    return (unsigned short)(u >> 16);
}
__device__ __forceinline__ float bf2f(unsigned short s) {
    return __builtin_bit_cast(float, ((unsigned)s) << 16);
}
__device__ __forceinline__ float sigm(float x) {
    return __builtin_amdgcn_rcpf(1.0f + exp2f(-1.4426950408889634f * x));
}
__device__ __forceinline__ float tanh_f(float x) {
    return 1.0f - 2.0f * __builtin_amdgcn_rcpf(1.0f + exp2f(2.8853900817779268f * x));
}

// Weights to bf16, layout [k8][col][8]: elem (col, k=k8*8+e) at (k8*256+col)*8+e.
// w0: 48 k8 (K=384); per gate wg: 80 k8 (K=640: h|x|s), gates f,i,T,u,o.
__global__ void convert_w(const float* __restrict__ Wh, const float* __restrict__ Wx,
                          const float* __restrict__ Ws, unsigned short* __restrict__ w0,
                          unsigned short* __restrict__ wg) {
    const int t  = blockIdx.x * blockDim.x + threadIdx.x;
    const int N0 = 48 * 2048;        // 98304
    const int N1 = 5 * 80 * 2048;    // 819200
    if (t < N0) {
        const int k8 = t >> 11, rem = t & 2047;
        const int col = rem >> 3, e = rem & 7;
        const int k = k8 * 8 + e;
        const float v = (k < H) ? Wh[col * H + k] : Wx[col * I + (k - H)];
        w0[t] = f2bf(v);
    } else if (t < N0 + N1) {
        const int u   = t - N0;
        const int g1  = u / 163840;
        const int rem = u - g1 * 163840;
        const int k8  = rem >> 11;
        const int r2  = rem & 2047;
        const int col = r2 >> 3, e = r2 & 7;
        const int k   = k8 * 8 + e;
        const int g   = g1 + 1;
        float v;
        if (k < H)        v = Wh[g * H * H + col * H + k];
        else if (k < K1)  v = Wx[g * H * I + col * I + (k - H)];
        else              v = Ws[g1 * H * H + col * H + (k - K1)];
        wg[u] = f2bf(v);
    }
}

// K-loop: 1 A stream, 1 B stream, single acc chain. Ring depth 2.
template<int NIT>
__device__ __forceinline__ void gemm1(const unsigned char* Ab, int abase,
        const unsigned short* __restrict__ Wp, f32x16& acc) {
    bf16x8 b[2], a[2];
    #pragma unroll
    for (int i = 0; i < 2; ++i) {
        b[i] = *(const bf16x8*)(Wp + i * 4096);
        a[i] = *(const bf16x8*)(Ab + abase + i * 1024);
    }
    #pragma unroll
    for (int i = 0; i < NIT; ++i) {
        const bf16x8 av = a[i & 1], bv = b[i & 1];
        if (i + 2 < NIT) {
            a[i & 1] = *(const bf16x8*)(Ab + abase + (i + 2) * 1024);
            b[i & 1] = *(const bf16x8*)(Wp + (i + 2) * 4096);
        }
        acc = __builtin_amdgcn_mfma_f32_32x32x16_bf16(av, bv, acc, 0, 0, 0);
    }
}

__global__ __launch_bounds__(NTHR, 4) void thlstm_fused(
        const float* __restrict__ x_t, const float* __restrict__ delta_t,
        const float* __restrict__ h_prev, const float* __restrict__ c_prev,
        const float* __restrict__ Wst, const float* __restrict__ bias,
        const unsigned short* __restrict__ w0, const unsigned short* __restrict__ wg,
        float* __restrict__ out) {
    __shared__ __align__(16) unsigned char Abuf[40960];   // 24KB hx + 16KB s
    const int tid = threadIdx.x;
    const int b0  = blockIdx.x * BT;

    // ---- stage h|x bf16, fragment order: chunk (k8, row) at (k8*32+row)*16 ----
    #pragma unroll
    for (int it = 0; it < 3; ++it) {
        const int c   = it * NTHR + tid;
        const int k8  = c >> 5, row = c & 31;
        const float* src = (k8 < 32) ? (h_prev + (size_t)(b0 + row) * H + k8 * 8)
                                     : (x_t    + (size_t)(b0 + row) * I + (k8 - 32) * 8);
        const float4 v0 = ((const float4*)src)[0];
        const float4 v1 = ((const float4*)src)[1];
        ushort8 p;
        p[0] = f2bf(v0.x); p[1] = f2bf(v0.y); p[2] = f2bf(v0.z); p[3] = f2bf(v0.w);
        p[4] = f2bf(v1.x); p[5] = f2bf(v1.y); p[6] = f2bf(v1.z); p[7] = f2bf(v1.w);
        *(ushort8*)(Abuf + (k8 * 32 + row) * 16) = p;
    }
    __syncthreads();

    const int lane  = tid & 63;
    const int wv    = tid >> 6;           // 0..7 -> cols wv*32 .. wv*32+31
    const int half  = lane >> 5;
    const int l31   = lane & 31;
    const int ocol  = wv * 32 + l31;
    const int rbase = 4 * half;
    const int abase = half * 512 + l31 * 16;
    const int wlo   = half * 2048 + ocol * 8;                       // shorts
    const int sbase = SOFF + ((ocol >> 3) * 32) * 16 + (ocol & 7) * 2;

    // ---- gate s: K=384 ----
    {
        f32x16 acc;
        #pragma unroll
        for (int r = 0; r < 16; ++r) acc[r] = 0.f;
        gemm1<24>(Abuf, abase, w0 + wlo, acc);
        const float wst = Wst[ocol];
        const float bs  = bias[ocol];
        #pragma unroll
        for (int r = 0; r < 16; ++r) {
            const int mrow = (r & 3) + 8 * (r >> 2) + rbase;
            const float sv = tanh_f(acc[r] + delta_t[b0 + mrow] * wst + bs);
            *(unsigned short*)(Abuf + sbase + mrow * 16) = f2bf(sv);
        }
    }
    __syncthreads();

    float    cacc[16];
    unsigned ipk[8];

    // ---- gate f (wg 0, bias 1): c = f * c_prev ----
    {
        f32x16 ac;
        #pragma unroll
        for (int r = 0; r < 16; ++r) ac[r] = 0.f;
        gemm1<40>(Abuf, abase, wg + 0 * 163840 + wlo, ac);
        const float bg = bias[1 * H + ocol];
        #pragma unroll
        for (int r = 0; r < 16; ++r) {
            const int mrow = (r & 3) + 8 * (r >> 2) + rbase;
            const size_t idx = (size_t)(b0 + mrow) * H + ocol;
            cacc[r] = sigm(ac[r] + bg) * c_prev[idx];
        }
    }
    // ---- gate T (wg 2, bias 3): c += T * s (s from LDS) ----
    {
        f32x16 ac;
        #pragma unroll
        for (int r = 0; r < 16; ++r) ac[r] = 0.f;
        gemm1<40>(Abuf, abase, wg + 2 * 163840 + wlo, ac);
        const float bg = bias[3 * H + ocol];
        #pragma unroll
        for (int r = 0; r < 16; ++r) {
            const int mrow = (r & 3) + 8 * (r >> 2) + rbase;
            const float sv = bf2f(*(const unsigned short*)(Abuf + sbase + mrow * 16));
            cacc[r] += sigm(ac[r] + bg) * sv;
        }
    }
    // ---- gate i (wg 1, bias 2): keep packed ----
    {
        f32x16 ac;
        #pragma unroll
        for (int r = 0; r < 16; ++r) ac[r] = 0.f;
        gemm1<40>(Abuf, abase, wg + 1 * 163840 + wlo, ac);
        const float bg = bias[2 * H + ocol];
        float tmpf = 0.f;
        #pragma unroll
        for (int r = 0; r < 16; ++r) {
            const float sg = sigm(ac[r] + bg);
            if ((r & 1) == 0) tmpf = sg;
            else ipk[r >> 1] = (unsigned)f2bf(tmpf) | ((unsigned)f2bf(sg) << 16);
        }
    }
    // ---- gate u (wg 3, bias 4): c += i * tanh(u) ----
    {
        f32x16 ac;
        #pragma unroll
        for (int r = 0; r < 16; ++r) ac[r] = 0.f;
        gemm1<40>(Abuf, abase, wg + 3 * 163840 + wlo, ac);
        const float bg = bias[4 * H + ocol];
        #pragma unroll
        for (int r = 0; r < 16; ++r) {
            const float iv = bf2f((unsigned short)((ipk[r >> 1] >> ((r & 1) * 16)) & 0xffffu));
            cacc[r] += iv * tanh_f(ac[r] + bg);
        }
    }
    // ---- gate o (wg 4, bias 5): outputs ----
    {
        f32x16 ac;
        #pragma unroll
        for (int r = 0; r < 16; ++r) ac[r] = 0.f;
        gemm1<40>(Abuf, abase, wg + 4 * 163840 + wlo, ac);
        const float bg = bias[5 * H + ocol];
        #pragma unroll
        for (int r = 0; r < 16; ++r) {
            const int mrow = (r & 3) + 8 * (r >> 2) + rbase;
            const size_t idx = (size_t)(b0 + mrow) * H + ocol;
            const float c = cacc[r];
            out[idx] = sigm(ac[r] + bg) * tanh_f(c);
            out[(size_t)Btot * H + idx] = c;
        }
    }
}

extern "C" void kernel_launch(void* const* d_in, const int* in_sizes, int n_in,
                              void* d_out, int out_size, void* d_ws, size_t ws_size,
                              hipStream_t stream) {
    (void)in_sizes; (void)n_in; (void)out_size; (void)ws_size;
    const float* x_t    = (const float*)d_in[0];
    const float* delta  = (const float*)d_in[1];
    const float* h_prev = (const float*)d_in[2];
    const float* c_prev = (const float*)d_in[3];
    const float* Wh     = (const float*)d_in[4];
    const float* Wx     = (const float*)d_in[5];
    const float* Ws     = (const float*)d_in[6];
    const float* Wst    = (const float*)d_in[7];
    const float* bias   = (const float*)d_in[8];
    float* out = (float*)d_out;

    unsigned short* w0 = (unsigned short*)d_ws;   // 48*2048 bf16
    unsigned short* wg = w0 + 48 * 2048;          // 5*80*2048 bf16

    const int total = 48 * 2048 + 5 * 80 * 2048;  // 917504
    convert_w<<<(total + 255) / 256, 256, 0, stream>>>(Wh, Wx, Ws, w0, wg);
    thlstm_fused<<<Btot / BT, NTHR, 0, stream>>>(x_t, delta, h_prev, c_prev,
                                                 Wst, bias, w0, wg, out);
}